// Round 1
// baseline (2423.390 us; speedup 1.0000x reference)
//
#include <hip/hip_runtime.h>
#include <cstddef>

#define Nn 50000
#define Ee 500000
#define INC 128
#define HC 256      // HEADS*OUT_C
#define OUTC 64
#define EDIM 32
#define NEG 0.2f

// ---- ordered-uint encoding for float atomic max ----
__device__ __forceinline__ unsigned fenc(float f) {
    unsigned u = __float_as_uint(f);
    return (u & 0x80000000u) ? ~u : (u | 0x80000000u);
}
__device__ __forceinline__ float fdec(unsigned k) {
    unsigned u = (k & 0x80000000u) ? (k & 0x7FFFFFFFu) : ~k;
    return __uint_as_float(u);
}

// ---- K0: init out=bias, amax=0 (== -inf key), denom=0 ----
__global__ __launch_bounds__(256) void init_kernel(
    float* __restrict__ out, const float* __restrict__ bias,
    unsigned* __restrict__ amax, float* __restrict__ denom)
{
    int idx = blockIdx.x * 256 + threadIdx.x;
    if (idx < Nn * OUTC) out[idx] = bias[idx & (OUTC - 1)];
    if (idx < Nn * 4) { amax[idx] = 0u; denom[idx] = 0.f; }
}

// ---- K1: Y = X @ W + b for both (W_l,b_l)->Yl and (W_r,b_r)->Yr (blockIdx.z) ----
// BM=64, BN=64, K=128 staged fully in LDS. 256 threads, 4x4 microtile.
__global__ __launch_bounds__(256) void gemm_kernel(
    const float* __restrict__ X,
    const float* __restrict__ Wl, const float* __restrict__ bl,
    const float* __restrict__ Wr, const float* __restrict__ br,
    float* __restrict__ Yl, float* __restrict__ Yr)
{
    const float* W; const float* b; float* Y;
    if (blockIdx.z == 0) { W = Wl; b = bl; Y = Yl; } else { W = Wr; b = br; Y = Yr; }

    __shared__ float sA[64][132];   // 132: 16B-aligned rows, conflict-ok
    __shared__ float sB[128][68];   // 68:  16B-aligned rows

    int row0 = blockIdx.x * 64, col0 = blockIdx.y * 64;
    int tid = threadIdx.x;

    { // stage A: 64 x 128
        int r = tid >> 5, c4 = (tid & 31) << 2;
        #pragma unroll
        for (int rr = 0; rr < 64; rr += 8) {
            int grow = row0 + r + rr;
            float4 v = make_float4(0.f, 0.f, 0.f, 0.f);
            if (grow < Nn) v = *(const float4*)(X + (size_t)grow * INC + c4);
            *(float4*)(&sA[r + rr][c4]) = v;
        }
    }
    { // stage B: 128 x 64
        int k = tid >> 4, c4 = (tid & 15) << 2;
        #pragma unroll
        for (int kk = 0; kk < 128; kk += 16) {
            float4 v = *(const float4*)(W + (size_t)(k + kk) * HC + col0 + c4);
            *(float4*)(&sB[k + kk][c4]) = v;
        }
    }
    __syncthreads();

    int ty = tid >> 4, tx = tid & 15;
    float acc[4][4] = {};
    for (int k = 0; k < 128; k += 4) {
        float4 a[4];
        #pragma unroll
        for (int i = 0; i < 4; ++i) a[i] = *(const float4*)(&sA[ty * 4 + i][k]);
        #pragma unroll
        for (int kk = 0; kk < 4; ++kk) {
            float4 bv = *(const float4*)(&sB[k + kk][tx * 4]);
            #pragma unroll
            for (int i = 0; i < 4; ++i) {
                float av = (kk == 0) ? a[i].x : (kk == 1) ? a[i].y : (kk == 2) ? a[i].z : a[i].w;
                acc[i][0] += av * bv.x; acc[i][1] += av * bv.y;
                acc[i][2] += av * bv.z; acc[i][3] += av * bv.w;
            }
        }
    }

    float4 bv = *(const float4*)(b + col0 + tx * 4);
    #pragma unroll
    for (int i = 0; i < 4; ++i) {
        int grow = row0 + ty * 4 + i;
        if (grow < Nn) {
            float4 o = make_float4(acc[i][0] + bv.x, acc[i][1] + bv.y,
                                   acc[i][2] + bv.z, acc[i][3] + bv.w);
            *(float4*)(Y + (size_t)grow * HC + col0 + tx * 4) = o;
        }
    }
}

// ---- K2: per-edge logits alpha[e,h] = att_h . leaky(xl[s]+xr[d]+ea@We), atomicMax amax ----
// one wave per edge, 4 channels/lane, W_e in LDS, grid-stride over edges
__global__ __launch_bounds__(256) void edge_alpha_kernel(
    const float* __restrict__ xl, const float* __restrict__ xr,
    const int* __restrict__ ei, const float* __restrict__ ea,
    const float* __restrict__ We, const float* __restrict__ att,
    float* __restrict__ alpha, unsigned* __restrict__ amax)
{
    __shared__ float sWe[EDIM * HC];   // 32 KB
    __shared__ float sAtt[HC];
    int tid = threadIdx.x;
    for (int i = tid; i < EDIM * HC; i += 256) sWe[i] = We[i];
    if (tid < HC) sAtt[tid] = att[tid];
    __syncthreads();

    int lane = tid & 63;
    int wid = blockIdx.x * 4 + (tid >> 6);
    int nw = gridDim.x * 4;
    int c = lane << 2;
    float4 at = *(const float4*)(sAtt + c);

    for (int e = wid; e < Ee; e += nw) {
        int s = ei[e], d = ei[Ee + e];
        float4 vl = *(const float4*)(xl + (size_t)s * HC + c);
        float4 vr = *(const float4*)(xr + (size_t)d * HC + c);
        float eav = (lane < EDIM) ? ea[(size_t)e * EDIM + lane] : 0.f;
        float4 ev = make_float4(0.f, 0.f, 0.f, 0.f);
        #pragma unroll
        for (int dd = 0; dd < EDIM; ++dd) {
            float a = __shfl(eav, dd, 64);
            float4 w = *(const float4*)(sWe + dd * HC + c);
            ev.x += a * w.x; ev.y += a * w.y; ev.z += a * w.z; ev.w += a * w.w;
        }
        float4 m = make_float4(vl.x + vr.x + ev.x, vl.y + vr.y + ev.y,
                               vl.z + vr.z + ev.z, vl.w + vr.w + ev.w);
        m.x = m.x > 0.f ? m.x : NEG * m.x;
        m.y = m.y > 0.f ? m.y : NEG * m.y;
        m.z = m.z > 0.f ? m.z : NEG * m.z;
        m.w = m.w > 0.f ? m.w : NEG * m.w;
        float p = m.x * at.x + m.y * at.y + m.z * at.z + m.w * at.w;
        p += __shfl_xor(p, 1, 64);
        p += __shfl_xor(p, 2, 64);
        p += __shfl_xor(p, 4, 64);
        p += __shfl_xor(p, 8, 64);
        if ((lane & 15) == 0) {
            int h = lane >> 4;
            alpha[(size_t)e * 4 + h] = p;
            atomicMax(amax + (size_t)d * 4 + h, fenc(p));
        }
    }
}

// ---- K3: alpha <- exp(alpha - amax[dst]); denom[dst] += alpha ----
__global__ __launch_bounds__(256) void edge_exp_kernel(
    const int* __restrict__ ei, float* __restrict__ alpha,
    const unsigned* __restrict__ amax, float* __restrict__ denom)
{
    int idx = blockIdx.x * 256 + threadIdx.x;
    if (idx >= Ee * 4) return;
    int e = idx >> 2, h = idx & 3;
    int d = ei[Ee + e];
    float mx = fdec(amax[(size_t)d * 4 + h]);
    float v = __expf(alpha[idx] - mx);
    alpha[idx] = v;
    atomicAdd(denom + (size_t)d * 4 + h, v);
}

// ---- K4: out[dst,c] += 0.25 * sum_h (alpha/denom) * xl[src,h,c] ----
// one wave per edge, lane = output channel
__global__ __launch_bounds__(256) void edge_aggr_kernel(
    const float* __restrict__ xl, const int* __restrict__ ei,
    const float* __restrict__ alpha, const float* __restrict__ denom,
    float* __restrict__ out)
{
    int lane = threadIdx.x & 63;
    int e = blockIdx.x * 4 + (threadIdx.x >> 6);
    if (e >= Ee) return;
    int s = ei[e], d = ei[Ee + e];
    float acc = 0.f;
    #pragma unroll
    for (int h = 0; h < 4; ++h) {
        float w = 0.25f * alpha[(size_t)e * 4 + h] / denom[(size_t)d * 4 + h];
        acc += w * xl[(size_t)s * HC + h * OUTC + lane];
    }
    atomicAdd(out + (size_t)d * OUTC + lane, acc);
}

extern "C" void kernel_launch(void* const* d_in, const int* in_sizes, int n_in,
                              void* d_out, int out_size, void* d_ws, size_t ws_size,
                              hipStream_t stream)
{
    const float* x    = (const float*)d_in[0];
    const int*   ei   = (const int*)d_in[1];     // [2,E] int32 (harness converts integer inputs)
    const float* ea   = (const float*)d_in[2];
    const float* Wl   = (const float*)d_in[3];
    const float* bl   = (const float*)d_in[4];
    const float* Wr   = (const float*)d_in[5];
    const float* br   = (const float*)d_in[6];
    const float* We   = (const float*)d_in[7];
    const float* att  = (const float*)d_in[8];
    const float* bias = (const float*)d_in[9];
    float* out = (float*)d_out;

    // workspace layout
    float*    xl    = (float*)d_ws;                       // N*256
    float*    xr    = xl + (size_t)Nn * HC;               // N*256
    float*    alpha = xr + (size_t)Nn * HC;               // E*4
    unsigned* amax  = (unsigned*)(alpha + (size_t)Ee * 4);// N*4
    float*    denom = (float*)(amax + (size_t)Nn * 4);    // N*4

    init_kernel<<<(Nn * OUTC + 255) / 256, 256, 0, stream>>>(out, bias, amax, denom);
    gemm_kernel<<<dim3((Nn + 63) / 64, HC / 64, 2), 256, 0, stream>>>(x, Wl, bl, Wr, br, xl, xr);
    edge_alpha_kernel<<<2048, 256, 0, stream>>>(xl, xr, ei, ea, We, att, alpha, amax);
    edge_exp_kernel<<<(Ee * 4 + 255) / 256, 256, 0, stream>>>(ei, alpha, amax, denom);
    edge_aggr_kernel<<<(Ee + 3) / 4, 256, 0, stream>>>(xl, ei, alpha, denom, out);
}

// Round 2
// 587.031 us; speedup vs baseline: 4.1282x; 4.1282x over previous
//
#include <hip/hip_runtime.h>
#include <cstddef>

#define Nn 50000
#define Ee 500000
#define INC 128
#define HC 256      // HEADS*OUT_C
#define OUTC 64
#define EDIM 32
#define NEG 0.2f
#define BK 32

// ---- ordered-uint encoding for float atomic max ----
__device__ __forceinline__ unsigned fenc(float f) {
    unsigned u = __float_as_uint(f);
    return (u & 0x80000000u) ? ~u : (u | 0x80000000u);
}
__device__ __forceinline__ float fdec(unsigned k) {
    unsigned u = (k & 0x80000000u) ? (k & 0x7FFFFFFFu) : ~k;
    return __uint_as_float(u);
}

// ---- K0: init out=bias, amax=0 (== -inf key), denom=0 ----
__global__ __launch_bounds__(256) void init_kernel(
    float* __restrict__ out, const float* __restrict__ bias,
    unsigned* __restrict__ amax, float* __restrict__ denom)
{
    int idx = blockIdx.x * 256 + threadIdx.x;
    if (idx < Nn * OUTC) out[idx] = bias[idx & (OUTC - 1)];
    if (idx < Nn * 4) { amax[idx] = 0u; denom[idx] = 0.f; }
}

// ---- K1: Y = X @ W + b, blockIdx.y selects (W_l,b_l)->Yl vs (W_r,b_r)->Yr ----
// Tile: 64 rows x 256 cols (full N), K chunked at BK=32.
// 256 threads; thread (ty=tid>>4, tx=tid&15) owns rows ty*4..+3, cols {tx*4 + j*64}.
// acc = 4x4 float4 = 64 VGPRs. unroll 1 on staged loops to avoid spill.
__global__ __launch_bounds__(256) void gemm_kernel(
    const float* __restrict__ X,
    const float* __restrict__ Wl, const float* __restrict__ bl,
    const float* __restrict__ Wr, const float* __restrict__ br,
    float* __restrict__ Yl, float* __restrict__ Yr)
{
    const float* W; const float* b; float* Y;
    if (blockIdx.y == 0) { W = Wl; b = bl; Y = Yl; } else { W = Wr; b = br; Y = Yr; }

    __shared__ float sA[64][36];   // rows 144B (16B multiple); 9 KB
    __shared__ float sB[BK][256];  // 32 KB

    const int row0 = blockIdx.x * 64;
    const int tid  = threadIdx.x;
    const int ty   = tid >> 4;     // 0..15 -> row group
    const int tx   = tid & 15;     // 0..15 -> col group

    float4 acc[4][4];
    #pragma unroll
    for (int i = 0; i < 4; ++i)
        #pragma unroll
        for (int j = 0; j < 4; ++j)
            acc[i][j] = make_float4(0.f, 0.f, 0.f, 0.f);

    #pragma unroll 1
    for (int k0 = 0; k0 < INC; k0 += BK) {
        if (k0) __syncthreads();
        // stage A: 64 x 32 (512 float4, 2 per thread)
        #pragma unroll
        for (int it = 0; it < 2; ++it) {
            int idx = tid + it * 256;
            int r = idx >> 3, c = (idx & 7) << 2;
            float4 v = make_float4(0.f, 0.f, 0.f, 0.f);
            if (row0 + r < Nn) v = *(const float4*)(X + (size_t)(row0 + r) * INC + k0 + c);
            *(float4*)(&sA[r][c]) = v;
        }
        // stage B: 32 x 256 (2048 float4, 8 per thread)
        #pragma unroll
        for (int it = 0; it < 8; ++it) {
            int idx = tid + it * 256;
            int k = idx >> 6, c = (idx & 63) << 2;
            *(float4*)(&sB[k][c]) = *(const float4*)(W + (size_t)(k0 + k) * HC + c);
        }
        __syncthreads();

        #pragma unroll 1
        for (int kk = 0; kk < BK; kk += 4) {
            float4 a[4];
            #pragma unroll
            for (int i = 0; i < 4; ++i) a[i] = *(const float4*)(&sA[ty * 4 + i][kk]);
            #pragma unroll
            for (int t = 0; t < 4; ++t) {
                float4 bv[4];
                #pragma unroll
                for (int j = 0; j < 4; ++j)
                    bv[j] = *(const float4*)(&sB[kk + t][tx * 4 + j * 64]);
                #pragma unroll
                for (int i = 0; i < 4; ++i) {
                    float av = (t == 0) ? a[i].x : (t == 1) ? a[i].y : (t == 2) ? a[i].z : a[i].w;
                    #pragma unroll
                    for (int j = 0; j < 4; ++j) {
                        acc[i][j].x += av * bv[j].x;
                        acc[i][j].y += av * bv[j].y;
                        acc[i][j].z += av * bv[j].z;
                        acc[i][j].w += av * bv[j].w;
                    }
                }
            }
        }
    }

    float4 bs[4];
    #pragma unroll
    for (int j = 0; j < 4; ++j) bs[j] = *(const float4*)(b + tx * 4 + j * 64);
    #pragma unroll
    for (int i = 0; i < 4; ++i) {
        int grow = row0 + ty * 4 + i;
        if (grow < Nn) {
            #pragma unroll
            for (int j = 0; j < 4; ++j) {
                float4 o = make_float4(acc[i][j].x + bs[j].x, acc[i][j].y + bs[j].y,
                                       acc[i][j].z + bs[j].z, acc[i][j].w + bs[j].w);
                *(float4*)(Y + (size_t)grow * HC + tx * 4 + j * 64) = o;
            }
        }
    }
}

// ---- K2: per-edge logits alpha[e,h] = att_h . leaky(xl[s]+xr[d]+ea@We), atomicMax amax ----
// one wave per edge, 4 channels/lane, W_e in LDS, grid-stride over edges
__global__ __launch_bounds__(256) void edge_alpha_kernel(
    const float* __restrict__ xl, const float* __restrict__ xr,
    const int* __restrict__ ei, const float* __restrict__ ea,
    const float* __restrict__ We, const float* __restrict__ att,
    float* __restrict__ alpha, unsigned* __restrict__ amax)
{
    __shared__ float sWe[EDIM * HC];   // 32 KB
    __shared__ float sAtt[HC];
    int tid = threadIdx.x;
    for (int i = tid; i < EDIM * HC; i += 256) sWe[i] = We[i];
    if (tid < HC) sAtt[tid] = att[tid];
    __syncthreads();

    int lane = tid & 63;
    int wid = blockIdx.x * 4 + (tid >> 6);
    int nw = gridDim.x * 4;
    int c = lane << 2;
    float4 at = *(const float4*)(sAtt + c);

    for (int e = wid; e < Ee; e += nw) {
        int s = ei[e], d = ei[Ee + e];
        float4 vl = *(const float4*)(xl + (size_t)s * HC + c);
        float4 vr = *(const float4*)(xr + (size_t)d * HC + c);
        float eav = (lane < EDIM) ? ea[(size_t)e * EDIM + lane] : 0.f;
        float4 ev = make_float4(0.f, 0.f, 0.f, 0.f);
        #pragma unroll
        for (int dd = 0; dd < EDIM; ++dd) {
            float a = __shfl(eav, dd, 64);
            float4 w = *(const float4*)(sWe + dd * HC + c);
            ev.x += a * w.x; ev.y += a * w.y; ev.z += a * w.z; ev.w += a * w.w;
        }
        float4 m = make_float4(vl.x + vr.x + ev.x, vl.y + vr.y + ev.y,
                               vl.z + vr.z + ev.z, vl.w + vr.w + ev.w);
        m.x = m.x > 0.f ? m.x : NEG * m.x;
        m.y = m.y > 0.f ? m.y : NEG * m.y;
        m.z = m.z > 0.f ? m.z : NEG * m.z;
        m.w = m.w > 0.f ? m.w : NEG * m.w;
        float p = m.x * at.x + m.y * at.y + m.z * at.z + m.w * at.w;
        p += __shfl_xor(p, 1, 64);
        p += __shfl_xor(p, 2, 64);
        p += __shfl_xor(p, 4, 64);
        p += __shfl_xor(p, 8, 64);
        if ((lane & 15) == 0) {
            int h = lane >> 4;
            alpha[(size_t)e * 4 + h] = p;
            atomicMax(amax + (size_t)d * 4 + h, fenc(p));
        }
    }
}

// ---- K3: alpha <- exp(alpha - amax[dst]); denom[dst] += alpha ----
__global__ __launch_bounds__(256) void edge_exp_kernel(
    const int* __restrict__ ei, float* __restrict__ alpha,
    const unsigned* __restrict__ amax, float* __restrict__ denom)
{
    int idx = blockIdx.x * 256 + threadIdx.x;
    if (idx >= Ee * 4) return;
    int e = idx >> 2, h = idx & 3;
    int d = ei[Ee + e];
    float mx = fdec(amax[(size_t)d * 4 + h]);
    float v = __expf(alpha[idx] - mx);
    alpha[idx] = v;
    atomicAdd(denom + (size_t)d * 4 + h, v);
}

// ---- K4: out[dst,c] += 0.25 * sum_h (alpha/denom) * xl[src,h,c] ----
// one wave per edge, lane = output channel
__global__ __launch_bounds__(256) void edge_aggr_kernel(
    const float* __restrict__ xl, const int* __restrict__ ei,
    const float* __restrict__ alpha, const float* __restrict__ denom,
    float* __restrict__ out)
{
    int lane = threadIdx.x & 63;
    int e = blockIdx.x * 4 + (threadIdx.x >> 6);
    if (e >= Ee) return;
    int s = ei[e], d = ei[Ee + e];
    float acc = 0.f;
    #pragma unroll
    for (int h = 0; h < 4; ++h) {
        float w = 0.25f * alpha[(size_t)e * 4 + h] / denom[(size_t)d * 4 + h];
        acc += w * xl[(size_t)s * HC + h * OUTC + lane];
    }
    atomicAdd(out + (size_t)d * OUTC + lane, acc);
}

extern "C" void kernel_launch(void* const* d_in, const int* in_sizes, int n_in,
                              void* d_out, int out_size, void* d_ws, size_t ws_size,
                              hipStream_t stream)
{
    const float* x    = (const float*)d_in[0];
    const int*   ei   = (const int*)d_in[1];
    const float* ea   = (const float*)d_in[2];
    const float* Wl   = (const float*)d_in[3];
    const float* bl   = (const float*)d_in[4];
    const float* Wr   = (const float*)d_in[5];
    const float* br   = (const float*)d_in[6];
    const float* We   = (const float*)d_in[7];
    const float* att  = (const float*)d_in[8];
    const float* bias = (const float*)d_in[9];
    float* out = (float*)d_out;

    // workspace layout
    float*    xl    = (float*)d_ws;                        // N*256
    float*    xr    = xl + (size_t)Nn * HC;                // N*256
    float*    alpha = xr + (size_t)Nn * HC;                // E*4
    unsigned* amax  = (unsigned*)(alpha + (size_t)Ee * 4); // N*4
    float*    denom = (float*)(amax + (size_t)Nn * 4);     // N*4

    init_kernel<<<(Nn * OUTC + 255) / 256, 256, 0, stream>>>(out, bias, amax, denom);
    gemm_kernel<<<dim3((Nn + 63) / 64, 2), 256, 0, stream>>>(x, Wl, bl, Wr, br, xl, xr);
    edge_alpha_kernel<<<2048, 256, 0, stream>>>(xl, xr, ei, ea, We, att, alpha, amax);
    edge_exp_kernel<<<(Ee * 4 + 255) / 256, 256, 0, stream>>>(ei, alpha, amax, denom);
    edge_aggr_kernel<<<(Ee + 3) / 4, 256, 0, stream>>>(xl, ei, alpha, denom, out);
}